// Round 4
// baseline (435.163 us; speedup 1.0000x reference)
//
#include <hip/hip_runtime.h>
#include <hip/hip_bf16.h>
#include <math.h>

// GNNConv rewrites:
//  (1) msg @ f_w = rel @ f_w[0:3] + x[src] @ f_w[3:]  -> per-node Yb (bf16) instead of per-edge GEMM
//  (2) dst-sorted aggregation, wave-per-dst, shfl-broadcast, zero atomics
//  (3) node_pre fuses delta + Yb (one read of x); gemm_g_fused fuses both g-layers (no hg round-trip)

#define LEAKY(v) ((v) >= 0.0f ? (v) : 0.01f * (v))

static __device__ __forceinline__ unsigned short f2bf(float f) {
    unsigned u = __float_as_uint(f);
    u = (u + 0x7fffu + ((u >> 16) & 1u)) >> 16;   // RNE
    return (unsigned short)u;
}

// ---------------- node_pre: delta = tanh(leaky(x@h_w1+h_b1)@h_w2+h_b2); Yb = bf16(x@f_w[3:]+f_b) ----
__global__ __launch_bounds__(256) void node_pre(
    const float* __restrict__ x,
    const float* __restrict__ h_w1, const float* __restrict__ h_b1,
    const float* __restrict__ h_w2, const float* __restrict__ h_b2,
    const float* __restrict__ f_w3p,  // f_w + 3*128
    const float* __restrict__ f_b,
    float* __restrict__ delta,        // [N,3]
    unsigned short* __restrict__ Yb,  // [N,128] bf16
    int N)
{
    __shared__ float As[16][132];
    __shared__ float Wh[16][128];
    __shared__ float Wf[16][128];
    __shared__ float W2s[128][3];
    __shared__ float red[128][3];

    const int tid = threadIdx.x;
    const int bn  = blockIdx.x * 128;
    const int tx  = tid & 15;
    const int ty  = tid >> 4;

    if (tid < 128) {
        W2s[tid][0] = h_w2[tid * 3 + 0];
        W2s[tid][1] = h_w2[tid * 3 + 1];
        W2s[tid][2] = h_w2[tid * 3 + 2];
        red[tid][0] = 0.f; red[tid][1] = 0.f; red[tid][2] = 0.f;
    }

    float acch[8][8], accf[8][8];
    #pragma unroll
    for (int i = 0; i < 8; ++i)
        #pragma unroll
        for (int j = 0; j < 8; ++j) { acch[i][j] = 0.f; accf[i][j] = 0.f; }

    #pragma unroll 1
    for (int k0 = 0; k0 < 128; k0 += 16) {
        {
            const int n  = tid >> 2;
            const int kq = (tid & 3) * 4;
            #pragma unroll
            for (int h = 0; h < 2; ++h) {
                const int nn  = n + h * 64;
                const int row = bn + nn;
                float4 v = make_float4(0.f, 0.f, 0.f, 0.f);
                if (row < N) v = *(const float4*)(x + (size_t)row * 128 + k0 + kq);
                As[kq + 0][nn] = v.x;
                As[kq + 1][nn] = v.y;
                As[kq + 2][nn] = v.z;
                As[kq + 3][nn] = v.w;
            }
        }
        {
            const int k = tid >> 4;
            const int j = (tid & 15) * 8;
            const float* wp = h_w1 + (size_t)(k0 + k) * 128 + j;
            *(float4*)&Wh[k][j]     = *(const float4*)(wp);
            *(float4*)&Wh[k][j + 4] = *(const float4*)(wp + 4);
            const float* fp = f_w3p + (size_t)(k0 + k) * 128 + j;
            *(float4*)&Wf[k][j]     = *(const float4*)(fp);
            *(float4*)&Wf[k][j + 4] = *(const float4*)(fp + 4);
        }
        __syncthreads();

        #pragma unroll
        for (int kk = 0; kk < 16; ++kk) {
            float a[8], wh[8], wf[8];
            *(float4*)&a[0]  = *(float4*)&As[kk][ty * 8];
            *(float4*)&a[4]  = *(float4*)&As[kk][ty * 8 + 4];
            *(float4*)&wh[0] = *(float4*)&Wh[kk][tx * 8];
            *(float4*)&wh[4] = *(float4*)&Wh[kk][tx * 8 + 4];
            *(float4*)&wf[0] = *(float4*)&Wf[kk][tx * 8];
            *(float4*)&wf[4] = *(float4*)&Wf[kk][tx * 8 + 4];
            #pragma unroll
            for (int i = 0; i < 8; ++i)
                #pragma unroll
                for (int j = 0; j < 8; ++j) {
                    acch[i][j] += a[i] * wh[j];
                    accf[i][j] += a[i] * wf[j];
                }
        }
        __syncthreads();
    }

    // delta reduction
    #pragma unroll
    for (int i = 0; i < 8; ++i) {
        float p0 = 0.f, p1 = 0.f, p2 = 0.f;
        #pragma unroll
        for (int jj = 0; jj < 8; ++jj) {
            const int col = tx * 8 + jj;
            float h = acch[i][jj] + h_b1[col];
            h = LEAKY(h);
            p0 += h * W2s[col][0];
            p1 += h * W2s[col][1];
            p2 += h * W2s[col][2];
        }
        const int rl = ty * 8 + i;
        atomicAdd(&red[rl][0], p0);
        atomicAdd(&red[rl][1], p1);
        atomicAdd(&red[rl][2], p2);
    }

    // Yb store (bf16), no activation
    #pragma unroll
    for (int i = 0; i < 8; ++i) {
        const int row = bn + ty * 8 + i;
        if (row < N) {
            const int col = tx * 8;
            ushort4 u0, u1;
            u0.x = f2bf(accf[i][0] + f_b[col + 0]);
            u0.y = f2bf(accf[i][1] + f_b[col + 1]);
            u0.z = f2bf(accf[i][2] + f_b[col + 2]);
            u0.w = f2bf(accf[i][3] + f_b[col + 3]);
            u1.x = f2bf(accf[i][4] + f_b[col + 4]);
            u1.y = f2bf(accf[i][5] + f_b[col + 5]);
            u1.z = f2bf(accf[i][6] + f_b[col + 6]);
            u1.w = f2bf(accf[i][7] + f_b[col + 7]);
            *(ushort4*)(Yb + (size_t)row * 128 + col)     = u0;
            *(ushort4*)(Yb + (size_t)row * 128 + col + 4) = u1;
        }
    }

    __syncthreads();
    if (tid < 128) {
        const int row = bn + tid;
        if (row < N) {
            delta[(size_t)row * 3 + 0] = tanhf(red[tid][0] + h_b2[0]);
            delta[(size_t)row * 3 + 1] = tanhf(red[tid][1] + h_b2[1]);
            delta[(size_t)row * 3 + 2] = tanhf(red[tid][2] + h_b2[2]);
        }
    }
}

// ---------------- counting sort of edges by dst ----------------
__global__ __launch_bounds__(256) void hist_kernel(
    const int* __restrict__ ei, int* __restrict__ counts, int E)
{
    const int e = blockIdx.x * 256 + threadIdx.x;
    if (e < E) atomicAdd(&counts[ei[(size_t)E + e]], 1);
}

__global__ __launch_bounds__(256) void scan_local(
    const int* __restrict__ counts, int* __restrict__ offs,
    int* __restrict__ blocksums, int N)
{
    __shared__ int s[256];
    const int tid  = threadIdx.x;
    const int base = blockIdx.x * 1024 + tid * 4;
    int v[4], sum = 0;
    #pragma unroll
    for (int j = 0; j < 4; ++j) {
        v[j] = (base + j < N) ? counts[base + j] : 0;
        sum += v[j];
    }
    s[tid] = sum;
    __syncthreads();
    for (int d = 1; d < 256; d <<= 1) {
        int t = (tid >= d) ? s[tid - d] : 0;
        __syncthreads();
        s[tid] += t;
        __syncthreads();
    }
    int run = s[tid] - sum;
    #pragma unroll
    for (int j = 0; j < 4; ++j) {
        if (base + j < N) offs[base + j] = run;
        run += v[j];
    }
    if (tid == 255) blocksums[blockIdx.x] = s[255];
}

__global__ __launch_bounds__(256) void scan_top(
    int* __restrict__ blocksums, int B)
{
    __shared__ int s[256];
    const int tid = threadIdx.x;
    int v[4], sum = 0;
    const int base = tid * 4;
    #pragma unroll
    for (int j = 0; j < 4; ++j) {
        v[j] = (base + j < B) ? blocksums[base + j] : 0;
        sum += v[j];
    }
    s[tid] = sum;
    __syncthreads();
    for (int d = 1; d < 256; d <<= 1) {
        int t = (tid >= d) ? s[tid - d] : 0;
        __syncthreads();
        s[tid] += t;
        __syncthreads();
    }
    int run = s[tid] - sum;
    #pragma unroll
    for (int j = 0; j < 4; ++j) {
        if (base + j < B) blocksums[base + j] = run;
        run += v[j];
    }
}

__global__ __launch_bounds__(256) void scan_fixup(
    int* __restrict__ offs, const int* __restrict__ blocksums, int N)
{
    const int i = blockIdx.x * 1024 + threadIdx.x * 4;
    const int add = blocksums[blockIdx.x];
    #pragma unroll
    for (int j = 0; j < 4; ++j)
        if (i + j < N) offs[i + j] += add;
}

__global__ __launch_bounds__(256) void scatter_kernel(
    const int* __restrict__ ei, int* __restrict__ offs,
    int* __restrict__ srcs_sorted, int E)
{
    const int e = blockIdx.x * 256 + threadIdx.x;
    if (e < E) {
        const int src = ei[e];
        const int dst = ei[(size_t)E + e];
        const int p = atomicAdd(&offs[dst], 1);
        srcs_sorted[p] = src;
    }
}

// ---------------- aggregation: wave-per-dst, bf16 Yb gather, shfl broadcast ----------------
__global__ __launch_bounds__(256) void aggregate_kernel(
    const int* __restrict__ srcs_sorted,
    const int* __restrict__ offs_end,      // start + count
    const int* __restrict__ counts,
    const float* __restrict__ pos,         // [N,3]
    const float* __restrict__ delta,       // [N,3]
    const unsigned short* __restrict__ Yb, // [N,128] bf16
    const float* __restrict__ fw3,         // [3][128]
    float* __restrict__ aggr,              // [N,128] = d_out
    int N)
{
    const int lane = threadIdx.x & 63;
    const int d = blockIdx.x * 4 + (threadIdx.x >> 6);
    if (d >= N) return;

    const int c = lane * 2;
    const float w00 = fw3[c],       w01 = fw3[c + 1];
    const float w10 = fw3[128 + c], w11 = fw3[129 + c];
    const float w20 = fw3[256 + c], w21 = fw3[257 + c];

    const int len   = counts[d];
    const int start = offs_end[d] - len;
    const float q0 = delta[(size_t)d * 3 + 0] - pos[(size_t)d * 3 + 0];
    const float q1 = delta[(size_t)d * 3 + 1] - pos[(size_t)d * 3 + 1];
    const float q2 = delta[(size_t)d * 3 + 2] - pos[(size_t)d * 3 + 2];

    float acc0 = 0.f, acc1 = 0.f;

    for (int chunk = 0; chunk < len; chunk += 64) {
        const int m = min(64, len - chunk);
        int idx = 0; float rx = 0.f, ry = 0.f, rz = 0.f;
        if (lane < m) {
            idx = srcs_sorted[start + chunk + lane];
            rx = pos[(size_t)idx * 3 + 0] + q0;
            ry = pos[(size_t)idx * 3 + 1] + q1;
            rz = pos[(size_t)idx * 3 + 2] + q2;
        }
        #pragma unroll 4
        for (int t = 0; t < m; ++t) {
            const int   s  = __shfl(idx, t);
            const float r0 = __shfl(rx, t);
            const float r1 = __shfl(ry, t);
            const float r2 = __shfl(rz, t);
            const unsigned int y = *(const unsigned int*)(Yb + (size_t)s * 128 + c);
            const float f0 = __uint_as_float((y & 0xffffu) << 16);
            const float f1 = __uint_as_float(y & 0xffff0000u);
            float z0 = f0 + r0 * w00 + r1 * w10 + r2 * w20;
            float z1 = f1 + r0 * w01 + r1 * w11 + r2 * w21;
            acc0 += LEAKY(z0);
            acc1 += LEAKY(z1);
        }
    }
    *(float2*)(aggr + (size_t)d * 128 + c) = make_float2(acc0, acc1);
}

// ---------------- fused g-MLP: out = leaky(aggr@g_w1+b1)@g_w2 + b2 + x  (in-place aggr==out OK) ----
__global__ __launch_bounds__(256) void gemm_g_fused(
    const float* __restrict__ aggr,
    const float* __restrict__ g_w1, const float* __restrict__ g_b1,
    const float* __restrict__ g_w2, const float* __restrict__ g_b2,
    const float* __restrict__ x,
    float* __restrict__ out,
    int N)
{
    __shared__ float As[16][132];
    __shared__ float Ws[16][128];

    const int tid = threadIdx.x;
    const int bn  = blockIdx.x * 128;
    const int tx  = tid & 15;
    const int ty  = tid >> 4;

    float acc[8][8];
    #pragma unroll
    for (int i = 0; i < 8; ++i)
        #pragma unroll
        for (int j = 0; j < 8; ++j) acc[i][j] = 0.f;

    // ---- phase 1: acc = aggr_tile @ g_w1 ----
    #pragma unroll 1
    for (int k0 = 0; k0 < 128; k0 += 16) {
        {
            const int n  = tid >> 2;
            const int kq = (tid & 3) * 4;
            #pragma unroll
            for (int h = 0; h < 2; ++h) {
                const int nn  = n + h * 64;
                const int row = bn + nn;
                float4 v = make_float4(0.f, 0.f, 0.f, 0.f);
                if (row < N) v = *(const float4*)(aggr + (size_t)row * 128 + k0 + kq);
                As[kq + 0][nn] = v.x;
                As[kq + 1][nn] = v.y;
                As[kq + 2][nn] = v.z;
                As[kq + 3][nn] = v.w;
            }
        }
        {
            const int k = tid >> 4;
            const int j = (tid & 15) * 8;
            const float* wp = g_w1 + (size_t)(k0 + k) * 128 + j;
            *(float4*)&Ws[k][j]     = *(const float4*)(wp);
            *(float4*)&Ws[k][j + 4] = *(const float4*)(wp + 4);
        }
        __syncthreads();

        #pragma unroll
        for (int kk = 0; kk < 16; ++kk) {
            float a[8], w[8];
            *(float4*)&a[0] = *(float4*)&As[kk][ty * 8];
            *(float4*)&a[4] = *(float4*)&As[kk][ty * 8 + 4];
            *(float4*)&w[0] = *(float4*)&Ws[kk][tx * 8];
            *(float4*)&w[4] = *(float4*)&Ws[kk][tx * 8 + 4];
            #pragma unroll
            for (int i = 0; i < 8; ++i)
                #pragma unroll
                for (int j = 0; j < 8; ++j)
                    acc[i][j] += a[i] * w[j];
        }
        __syncthreads();
    }

    // T = leaky(acc + b1), kept in registers
    float T[8][8];
    #pragma unroll
    for (int jj = 0; jj < 8; ++jj) {
        const float b = g_b1[tx * 8 + jj];
        #pragma unroll
        for (int i = 0; i < 8; ++i) {
            float t = acc[i][jj] + b;
            T[i][jj] = LEAKY(t);
        }
    }

    // ---- phase 2: acc2 = T @ g_w2, T round-trips through As in 16-col chunks ----
    float acc2[8][8];
    #pragma unroll
    for (int i = 0; i < 8; ++i)
        #pragma unroll
        for (int j = 0; j < 8; ++j) acc2[i][j] = 0.f;

    #pragma unroll 1
    for (int k0 = 0; k0 < 128; k0 += 16) {
        {
            const int k = tid >> 4;
            const int j = (tid & 15) * 8;
            const float* wp = g_w2 + (size_t)(k0 + k) * 128 + j;
            *(float4*)&Ws[k][j]     = *(const float4*)(wp);
            *(float4*)&Ws[k][j + 4] = *(const float4*)(wp + 4);
        }
        if ((tx >> 1) == (k0 >> 4)) {       // this tx group owns T cols k0..k0+15
            const int kkbase = tx * 8 - k0; // 0 or 8
            #pragma unroll
            for (int jj = 0; jj < 8; ++jj) {
                const int kk = kkbase + jj;
                float4 v0 = make_float4(T[0][jj], T[1][jj], T[2][jj], T[3][jj]);
                float4 v1 = make_float4(T[4][jj], T[5][jj], T[6][jj], T[7][jj]);
                *(float4*)&As[kk][ty * 8]     = v0;
                *(float4*)&As[kk][ty * 8 + 4] = v1;
            }
        }
        __syncthreads();

        #pragma unroll
        for (int kk = 0; kk < 16; ++kk) {
            float a[8], w[8];
            *(float4*)&a[0] = *(float4*)&As[kk][ty * 8];
            *(float4*)&a[4] = *(float4*)&As[kk][ty * 8 + 4];
            *(float4*)&w[0] = *(float4*)&Ws[kk][tx * 8];
            *(float4*)&w[4] = *(float4*)&Ws[kk][tx * 8 + 4];
            #pragma unroll
            for (int i = 0; i < 8; ++i)
                #pragma unroll
                for (int j = 0; j < 8; ++j)
                    acc2[i][j] += a[i] * w[j];
        }
        __syncthreads();
    }

    // epilogue: + b2 + x
    #pragma unroll
    for (int i = 0; i < 8; ++i) {
        const int row = bn + ty * 8 + i;
        if (row >= N) continue;
        const size_t base = (size_t)row * 128;
        #pragma unroll
        for (int j0 = 0; j0 < 8; j0 += 4) {
            const int col = tx * 8 + j0;
            const float4 b = *(const float4*)(g_b2 + col);
            const float4 r = *(const float4*)(x + base + col);
            float4 v;
            v.x = acc2[i][j0 + 0] + b.x + r.x;
            v.y = acc2[i][j0 + 1] + b.y + r.y;
            v.z = acc2[i][j0 + 2] + b.z + r.z;
            v.w = acc2[i][j0 + 3] + b.w + r.w;
            *(float4*)(out + base + col) = v;
        }
    }
}

// ---------------- launch ----------------
extern "C" void kernel_launch(void* const* d_in, const int* in_sizes, int n_in,
                              void* d_out, int out_size, void* d_ws, size_t ws_size,
                              hipStream_t stream) {
    const float* x    = (const float*)d_in[0];
    const float* pos  = (const float*)d_in[1];
    const int*   ei   = (const int*)d_in[2];
    const float* h_w1 = (const float*)d_in[3];
    const float* h_b1 = (const float*)d_in[4];
    const float* h_w2 = (const float*)d_in[5];
    const float* h_b2 = (const float*)d_in[6];
    const float* f_w  = (const float*)d_in[7];   // [131,128]
    const float* f_b  = (const float*)d_in[8];
    const float* g_w1 = (const float*)d_in[9];
    const float* g_b1 = (const float*)d_in[10];
    const float* g_w2 = (const float*)d_in[11];
    const float* g_b2 = (const float*)d_in[12];
    float* out = (float*)d_out;

    const int N = in_sizes[0] / 128;
    const int E = in_sizes[2] / 2;

    // ws (~19 MB): delta[N*3] f32 | Yb[N*128] bf16 | counts[N] | offs[N] | bsums[1024] | srcs[E]
    float* delta         = (float*)d_ws;
    unsigned short* Yb   = (unsigned short*)(delta + (size_t)N * 3);
    int* counts          = (int*)(Yb + (size_t)N * 128);
    int* offs            = counts + N;
    int* bsums           = offs + N;
    int* srcs            = bsums + 1024;
    float* aggr          = out;

    const int gemm_blocks = (N + 127) / 128;
    const int B = (N + 1023) / 1024;

    hipMemsetAsync(counts, 0, (size_t)N * sizeof(int), stream);

    node_pre<<<gemm_blocks, 256, 0, stream>>>(x, h_w1, h_b1, h_w2, h_b2,
                                              f_w + 3 * 128, f_b, delta, Yb, N);

    hist_kernel<<<(E + 255) / 256, 256, 0, stream>>>(ei, counts, E);
    scan_local<<<B, 256, 0, stream>>>(counts, offs, bsums, N);
    scan_top<<<1, 256, 0, stream>>>(bsums, B);
    scan_fixup<<<B, 256, 0, stream>>>(offs, bsums, N);
    scatter_kernel<<<(E + 255) / 256, 256, 0, stream>>>(ei, offs, srcs, E);

    aggregate_kernel<<<(N + 3) / 4, 256, 0, stream>>>(
        srcs, offs, counts, pos, delta, Yb, f_w, aggr, N);

    gemm_g_fused<<<gemm_blocks, 256, 0, stream>>>(aggr, g_w1, g_b1, g_w2, g_b2, x, out, N);
}

// Round 5
// 374.966 us; speedup vs baseline: 1.1605x; 1.1605x over previous
//
#include <hip/hip_runtime.h>
#include <hip/hip_bf16.h>
#include <math.h>

// GNNConv rewrites:
//  (1) msg @ f_w = rel @ f_w[0:3] + x[src] @ f_w[3:]  -> per-node Yb (bf16) instead of per-edge GEMM
//  (2) dst-sorted aggregation, wave-per-dst, shfl-broadcast, zero atomics
//  (3) node_pre fuses delta + Yb; gemm_g_fused fuses both g-layers
//  (4) r5: 64-row tiles (782 blocks, was 391 @ 8% occupancy), 2-way-free LDS bank layout
//      (cols tx*4 & 64+tx*4), shfl-based delta reduction (no LDS atomics)

#define LEAKY(v) ((v) >= 0.0f ? (v) : 0.01f * (v))

static __device__ __forceinline__ unsigned short f2bf(float f) {
    unsigned u = __float_as_uint(f);
    u = (u + 0x7fffu + ((u >> 16) & 1u)) >> 16;   // RNE
    return (unsigned short)u;
}

// ---------------- node_pre: delta = tanh(leaky(x@h_w1+h_b1)@h_w2+h_b2); Yb = bf16(x@f_w[3:]+f_b) ----
// 64-row tile, 256 threads: thread (tx=tid&15, ty=tid>>4) computes rows ty*4+i, cols {tx*4+j, 64+tx*4+j}
__global__ __launch_bounds__(256) void node_pre(
    const float* __restrict__ x,
    const float* __restrict__ h_w1, const float* __restrict__ h_b1,
    const float* __restrict__ h_w2, const float* __restrict__ h_b2,
    const float* __restrict__ f_w3p,  // f_w + 3*128
    const float* __restrict__ f_b,
    float* __restrict__ delta,        // [N,3]
    unsigned short* __restrict__ Yb,  // [N,128] bf16
    int N)
{
    __shared__ float As[16][68];
    __shared__ float Wh[16][128];
    __shared__ float Wf[16][128];
    __shared__ float W2s[128][3];
    __shared__ float red[64][3];

    const int tid = threadIdx.x;
    const int bn  = blockIdx.x * 64;
    const int tx  = tid & 15;
    const int ty  = tid >> 4;

    if (tid < 128) {
        W2s[tid][0] = h_w2[tid * 3 + 0];
        W2s[tid][1] = h_w2[tid * 3 + 1];
        W2s[tid][2] = h_w2[tid * 3 + 2];
    }

    float acch[4][8], accf[4][8];
    #pragma unroll
    for (int i = 0; i < 4; ++i)
        #pragma unroll
        for (int j = 0; j < 8; ++j) { acch[i][j] = 0.f; accf[i][j] = 0.f; }

    #pragma unroll 1
    for (int k0 = 0; k0 < 128; k0 += 16) {
        {   // A tile: 64 rows x 16 k -> As[k][n]
            const int n  = tid >> 2;          // 0..63
            const int kq = (tid & 3) * 4;     // 0,4,8,12
            const int row = bn + n;
            float4 v = make_float4(0.f, 0.f, 0.f, 0.f);
            if (row < N) v = *(const float4*)(x + (size_t)row * 128 + k0 + kq);
            As[kq + 0][n] = v.x;
            As[kq + 1][n] = v.y;
            As[kq + 2][n] = v.z;
            As[kq + 3][n] = v.w;
        }
        {   // W tiles: [k][j] with j = (tid&15)*4 and +64 (bank stride 4 -> 2-way, free)
            const int k = tid >> 4;           // 0..15
            const int j = (tid & 15) * 4;     // 0..60
            *(float4*)&Wh[k][j]      = *(const float4*)(h_w1  + (size_t)(k0 + k) * 128 + j);
            *(float4*)&Wh[k][j + 64] = *(const float4*)(h_w1  + (size_t)(k0 + k) * 128 + j + 64);
            *(float4*)&Wf[k][j]      = *(const float4*)(f_w3p + (size_t)(k0 + k) * 128 + j);
            *(float4*)&Wf[k][j + 64] = *(const float4*)(f_w3p + (size_t)(k0 + k) * 128 + j + 64);
        }
        __syncthreads();

        #pragma unroll
        for (int kk = 0; kk < 16; ++kk) {
            float a[4], wh[8], wf[8];
            *(float4*)&a[0]  = *(float4*)&As[kk][ty * 4];
            *(float4*)&wh[0] = *(float4*)&Wh[kk][tx * 4];
            *(float4*)&wh[4] = *(float4*)&Wh[kk][64 + tx * 4];
            *(float4*)&wf[0] = *(float4*)&Wf[kk][tx * 4];
            *(float4*)&wf[4] = *(float4*)&Wf[kk][64 + tx * 4];
            #pragma unroll
            for (int i = 0; i < 4; ++i)
                #pragma unroll
                for (int j = 0; j < 8; ++j) {
                    acch[i][j] += a[i] * wh[j];
                    accf[i][j] += a[i] * wf[j];
                }
        }
        __syncthreads();
    }

    // delta partials: h = leaky(acch + b1); p = h @ W2s. Row rl=ty*4+i is owned by the 16
    // consecutive lanes (same ty) of ONE wave -> shfl tree, tx==0 stores. No atomics.
    #pragma unroll
    for (int i = 0; i < 4; ++i) {
        float p0 = 0.f, p1 = 0.f, p2 = 0.f;
        #pragma unroll
        for (int jj = 0; jj < 8; ++jj) {
            const int col = (jj < 4) ? (tx * 4 + jj) : (64 + tx * 4 + jj - 4);
            float h = acch[i][jj] + h_b1[col];
            h = LEAKY(h);
            p0 += h * W2s[col][0];
            p1 += h * W2s[col][1];
            p2 += h * W2s[col][2];
        }
        #pragma unroll
        for (int off = 8; off; off >>= 1) {
            p0 += __shfl_down(p0, off);
            p1 += __shfl_down(p1, off);
            p2 += __shfl_down(p2, off);
        }
        if (tx == 0) {
            const int rl = ty * 4 + i;
            red[rl][0] = p0; red[rl][1] = p1; red[rl][2] = p2;
        }
    }

    // Yb store (bf16)
    #pragma unroll
    for (int i = 0; i < 4; ++i) {
        const int row = bn + ty * 4 + i;
        if (row < N) {
            const int c0 = tx * 4;
            ushort4 u0, u1;
            u0.x = f2bf(accf[i][0] + f_b[c0 + 0]);
            u0.y = f2bf(accf[i][1] + f_b[c0 + 1]);
            u0.z = f2bf(accf[i][2] + f_b[c0 + 2]);
            u0.w = f2bf(accf[i][3] + f_b[c0 + 3]);
            u1.x = f2bf(accf[i][4] + f_b[64 + c0 + 0]);
            u1.y = f2bf(accf[i][5] + f_b[64 + c0 + 1]);
            u1.z = f2bf(accf[i][6] + f_b[64 + c0 + 2]);
            u1.w = f2bf(accf[i][7] + f_b[64 + c0 + 3]);
            *(ushort4*)(Yb + (size_t)row * 128 + c0)      = u0;
            *(ushort4*)(Yb + (size_t)row * 128 + 64 + c0) = u1;
        }
    }

    __syncthreads();
    if (tid < 64) {
        const int row = bn + tid;
        if (row < N) {
            delta[(size_t)row * 3 + 0] = tanhf(red[tid][0] + h_b2[0]);
            delta[(size_t)row * 3 + 1] = tanhf(red[tid][1] + h_b2[1]);
            delta[(size_t)row * 3 + 2] = tanhf(red[tid][2] + h_b2[2]);
        }
    }
}

// ---------------- counting sort of edges by dst ----------------
__global__ __launch_bounds__(256) void hist_kernel(
    const int* __restrict__ ei, int* __restrict__ counts, int E)
{
    const int e = blockIdx.x * 256 + threadIdx.x;
    if (e < E) atomicAdd(&counts[ei[(size_t)E + e]], 1);
}

__global__ __launch_bounds__(256) void scan_local(
    const int* __restrict__ counts, int* __restrict__ offs,
    int* __restrict__ blocksums, int N)
{
    __shared__ int s[256];
    const int tid  = threadIdx.x;
    const int base = blockIdx.x * 1024 + tid * 4;
    int v[4], sum = 0;
    #pragma unroll
    for (int j = 0; j < 4; ++j) {
        v[j] = (base + j < N) ? counts[base + j] : 0;
        sum += v[j];
    }
    s[tid] = sum;
    __syncthreads();
    for (int d = 1; d < 256; d <<= 1) {
        int t = (tid >= d) ? s[tid - d] : 0;
        __syncthreads();
        s[tid] += t;
        __syncthreads();
    }
    int run = s[tid] - sum;
    #pragma unroll
    for (int j = 0; j < 4; ++j) {
        if (base + j < N) offs[base + j] = run;
        run += v[j];
    }
    if (tid == 255) blocksums[blockIdx.x] = s[255];
}

__global__ __launch_bounds__(256) void scan_top(
    int* __restrict__ blocksums, int B)
{
    __shared__ int s[256];
    const int tid = threadIdx.x;
    int v[4], sum = 0;
    const int base = tid * 4;
    #pragma unroll
    for (int j = 0; j < 4; ++j) {
        v[j] = (base + j < B) ? blocksums[base + j] : 0;
        sum += v[j];
    }
    s[tid] = sum;
    __syncthreads();
    for (int d = 1; d < 256; d <<= 1) {
        int t = (tid >= d) ? s[tid - d] : 0;
        __syncthreads();
        s[tid] += t;
        __syncthreads();
    }
    int run = s[tid] - sum;
    #pragma unroll
    for (int j = 0; j < 4; ++j) {
        if (base + j < B) blocksums[base + j] = run;
        run += v[j];
    }
}

__global__ __launch_bounds__(256) void scan_fixup(
    int* __restrict__ offs, const int* __restrict__ blocksums, int N)
{
    const int i = blockIdx.x * 1024 + threadIdx.x * 4;
    const int add = blocksums[blockIdx.x];
    #pragma unroll
    for (int j = 0; j < 4; ++j)
        if (i + j < N) offs[i + j] += add;
}

__global__ __launch_bounds__(256) void scatter_kernel(
    const int* __restrict__ ei, int* __restrict__ offs,
    int* __restrict__ srcs_sorted, int E)
{
    const int e = blockIdx.x * 256 + threadIdx.x;
    if (e < E) {
        const int src = ei[e];
        const int dst = ei[(size_t)E + e];
        const int p = atomicAdd(&offs[dst], 1);
        srcs_sorted[p] = src;
    }
}

// ---------------- aggregation: wave-per-dst, bf16 Yb gather, shfl broadcast ----------------
__global__ __launch_bounds__(256) void aggregate_kernel(
    const int* __restrict__ srcs_sorted,
    const int* __restrict__ offs_end,      // start + count
    const int* __restrict__ counts,
    const float* __restrict__ pos,         // [N,3]
    const float* __restrict__ delta,       // [N,3]
    const unsigned short* __restrict__ Yb, // [N,128] bf16
    const float* __restrict__ fw3,         // [3][128]
    float* __restrict__ aggr,              // [N,128] = d_out
    int N)
{
    const int lane = threadIdx.x & 63;
    const int d = blockIdx.x * 4 + (threadIdx.x >> 6);
    if (d >= N) return;

    const int c = lane * 2;
    const float w00 = fw3[c],       w01 = fw3[c + 1];
    const float w10 = fw3[128 + c], w11 = fw3[129 + c];
    const float w20 = fw3[256 + c], w21 = fw3[257 + c];

    const int len   = counts[d];
    const int start = offs_end[d] - len;
    const float q0 = delta[(size_t)d * 3 + 0] - pos[(size_t)d * 3 + 0];
    const float q1 = delta[(size_t)d * 3 + 1] - pos[(size_t)d * 3 + 1];
    const float q2 = delta[(size_t)d * 3 + 2] - pos[(size_t)d * 3 + 2];

    float acc0 = 0.f, acc1 = 0.f;

    for (int chunk = 0; chunk < len; chunk += 64) {
        const int m = min(64, len - chunk);
        int idx = 0; float rx = 0.f, ry = 0.f, rz = 0.f;
        if (lane < m) {
            idx = srcs_sorted[start + chunk + lane];
            rx = pos[(size_t)idx * 3 + 0] + q0;
            ry = pos[(size_t)idx * 3 + 1] + q1;
            rz = pos[(size_t)idx * 3 + 2] + q2;
        }
        #pragma unroll 4
        for (int t = 0; t < m; ++t) {
            const int   s  = __shfl(idx, t);
            const float r0 = __shfl(rx, t);
            const float r1 = __shfl(ry, t);
            const float r2 = __shfl(rz, t);
            const unsigned int y = *(const unsigned int*)(Yb + (size_t)s * 128 + c);
            const float f0 = __uint_as_float((y & 0xffffu) << 16);
            const float f1 = __uint_as_float(y & 0xffff0000u);
            float z0 = f0 + r0 * w00 + r1 * w10 + r2 * w20;
            float z1 = f1 + r0 * w01 + r1 * w11 + r2 * w21;
            acc0 += LEAKY(z0);
            acc1 += LEAKY(z1);
        }
    }
    *(float2*)(aggr + (size_t)d * 128 + c) = make_float2(acc0, acc1);
}

// ---------------- fused g-MLP: out = leaky(aggr@g_w1+b1)@g_w2 + b2 + x (in-place aggr==out OK) ----
// 64-row tile, same thread/col mapping as node_pre.
__global__ __launch_bounds__(256) void gemm_g_fused(
    const float* __restrict__ aggr,
    const float* __restrict__ g_w1, const float* __restrict__ g_b1,
    const float* __restrict__ g_w2, const float* __restrict__ g_b2,
    const float* __restrict__ x,
    float* __restrict__ out,
    int N)
{
    __shared__ float As[16][68];
    __shared__ float Ws[16][128];

    const int tid = threadIdx.x;
    const int bn  = blockIdx.x * 64;
    const int tx  = tid & 15;
    const int ty  = tid >> 4;

    float acc[4][8];
    #pragma unroll
    for (int i = 0; i < 4; ++i)
        #pragma unroll
        for (int j = 0; j < 8; ++j) acc[i][j] = 0.f;

    // ---- phase 1: acc = aggr_tile @ g_w1 ----
    #pragma unroll 1
    for (int k0 = 0; k0 < 128; k0 += 16) {
        {
            const int n  = tid >> 2;
            const int kq = (tid & 3) * 4;
            const int row = bn + n;
            float4 v = make_float4(0.f, 0.f, 0.f, 0.f);
            if (row < N) v = *(const float4*)(aggr + (size_t)row * 128 + k0 + kq);
            As[kq + 0][n] = v.x;
            As[kq + 1][n] = v.y;
            As[kq + 2][n] = v.z;
            As[kq + 3][n] = v.w;
        }
        {
            const int k = tid >> 4;
            const int j = (tid & 15) * 4;
            *(float4*)&Ws[k][j]      = *(const float4*)(g_w1 + (size_t)(k0 + k) * 128 + j);
            *(float4*)&Ws[k][j + 64] = *(const float4*)(g_w1 + (size_t)(k0 + k) * 128 + j + 64);
        }
        __syncthreads();

        #pragma unroll
        for (int kk = 0; kk < 16; ++kk) {
            float a[4], w[8];
            *(float4*)&a[0] = *(float4*)&As[kk][ty * 4];
            *(float4*)&w[0] = *(float4*)&Ws[kk][tx * 4];
            *(float4*)&w[4] = *(float4*)&Ws[kk][64 + tx * 4];
            #pragma unroll
            for (int i = 0; i < 4; ++i)
                #pragma unroll
                for (int j = 0; j < 8; ++j)
                    acc[i][j] += a[i] * w[j];
        }
        __syncthreads();
    }

    // T = leaky(acc + b1) in registers
    float T[4][8];
    #pragma unroll
    for (int jj = 0; jj < 8; ++jj) {
        const int col = (jj < 4) ? (tx * 4 + jj) : (64 + tx * 4 + jj - 4);
        const float b = g_b1[col];
        #pragma unroll
        for (int i = 0; i < 4; ++i) {
            float t = acc[i][jj] + b;
            T[i][jj] = LEAKY(t);
        }
    }

    // ---- phase 2: acc2 = T @ g_w2; T round-trips through As in 16-col chunks ----
    float acc2[4][8];
    #pragma unroll
    for (int i = 0; i < 4; ++i)
        #pragma unroll
        for (int j = 0; j < 8; ++j) acc2[i][j] = 0.f;

    #pragma unroll 1
    for (int k0 = 0; k0 < 128; k0 += 16) {
        {
            const int k = tid >> 4;
            const int j = (tid & 15) * 4;
            *(float4*)&Ws[k][j]      = *(const float4*)(g_w2 + (size_t)(k0 + k) * 128 + j);
            *(float4*)&Ws[k][j + 64] = *(const float4*)(g_w2 + (size_t)(k0 + k) * 128 + j + 64);
        }
        {   // stage T cols [k0,k0+16) into As[kk][row]
            const int kb   = (k0 < 64) ? k0 : (k0 - 64);
            const int txlo = kb >> 2;
            if (tx >= txlo && tx < txlo + 4) {
                const int jjb = (k0 < 64) ? 0 : 4;
                #pragma unroll
                for (int jo = 0; jo < 4; ++jo) {
                    const int kk = tx * 4 + jo - kb;   // 0..15
                    *(float4*)&As[kk][ty * 4] =
                        make_float4(T[0][jjb + jo], T[1][jjb + jo],
                                    T[2][jjb + jo], T[3][jjb + jo]);
                }
            }
        }
        __syncthreads();

        #pragma unroll
        for (int kk = 0; kk < 16; ++kk) {
            float a[4], w[8];
            *(float4*)&a[0] = *(float4*)&As[kk][ty * 4];
            *(float4*)&w[0] = *(float4*)&Ws[kk][tx * 4];
            *(float4*)&w[4] = *(float4*)&Ws[kk][64 + tx * 4];
            #pragma unroll
            for (int i = 0; i < 4; ++i)
                #pragma unroll
                for (int j = 0; j < 8; ++j)
                    acc2[i][j] += a[i] * w[j];
        }
        __syncthreads();
    }

    // epilogue: + b2 + x
    #pragma unroll
    for (int i = 0; i < 4; ++i) {
        const int row = bn + ty * 4 + i;
        if (row >= N) continue;
        const size_t base = (size_t)row * 128;
        const int c0 = tx * 4;
        float4 b0 = *(const float4*)(g_b2 + c0);
        float4 r0 = *(const float4*)(x + base + c0);
        float4 v0;
        v0.x = acc2[i][0] + b0.x + r0.x;
        v0.y = acc2[i][1] + b0.y + r0.y;
        v0.z = acc2[i][2] + b0.z + r0.z;
        v0.w = acc2[i][3] + b0.w + r0.w;
        *(float4*)(out + base + c0) = v0;
        float4 b1 = *(const float4*)(g_b2 + 64 + c0);
        float4 r1 = *(const float4*)(x + base + 64 + c0);
        float4 v1;
        v1.x = acc2[i][4] + b1.x + r1.x;
        v1.y = acc2[i][5] + b1.y + r1.y;
        v1.z = acc2[i][6] + b1.z + r1.z;
        v1.w = acc2[i][7] + b1.w + r1.w;
        *(float4*)(out + base + 64 + c0) = v1;
    }
}

// ---------------- launch ----------------
extern "C" void kernel_launch(void* const* d_in, const int* in_sizes, int n_in,
                              void* d_out, int out_size, void* d_ws, size_t ws_size,
                              hipStream_t stream) {
    const float* x    = (const float*)d_in[0];
    const float* pos  = (const float*)d_in[1];
    const int*   ei   = (const int*)d_in[2];
    const float* h_w1 = (const float*)d_in[3];
    const float* h_b1 = (const float*)d_in[4];
    const float* h_w2 = (const float*)d_in[5];
    const float* h_b2 = (const float*)d_in[6];
    const float* f_w  = (const float*)d_in[7];   // [131,128]
    const float* f_b  = (const float*)d_in[8];
    const float* g_w1 = (const float*)d_in[9];
    const float* g_b1 = (const float*)d_in[10];
    const float* g_w2 = (const float*)d_in[11];
    const float* g_b2 = (const float*)d_in[12];
    float* out = (float*)d_out;

    const int N = in_sizes[0] / 128;
    const int E = in_sizes[2] / 2;

    // ws (~19 MB): delta[N*3] f32 | Yb[N*128] bf16 | counts[N] | offs[N] | bsums[1024] | srcs[E]
    float* delta         = (float*)d_ws;
    unsigned short* Yb   = (unsigned short*)(delta + (size_t)N * 3);
    int* counts          = (int*)(Yb + (size_t)N * 128);
    int* offs            = counts + N;
    int* bsums           = offs + N;
    int* srcs            = bsums + 1024;
    float* aggr          = out;

    const int tile_blocks = (N + 63) / 64;     // 782
    const int B = (N + 1023) / 1024;

    hipMemsetAsync(counts, 0, (size_t)N * sizeof(int), stream);

    node_pre<<<tile_blocks, 256, 0, stream>>>(x, h_w1, h_b1, h_w2, h_b2,
                                              f_w + 3 * 128, f_b, delta, Yb, N);

    hist_kernel<<<(E + 255) / 256, 256, 0, stream>>>(ei, counts, E);
    scan_local<<<B, 256, 0, stream>>>(counts, offs, bsums, N);
    scan_top<<<1, 256, 0, stream>>>(bsums, B);
    scan_fixup<<<B, 256, 0, stream>>>(offs, bsums, N);
    scatter_kernel<<<(E + 255) / 256, 256, 0, stream>>>(ei, offs, srcs, E);

    aggregate_kernel<<<(N + 3) / 4, 256, 0, stream>>>(
        srcs, offs, counts, pos, delta, Yb, f_w, aggr, N);

    gemm_g_fused<<<tile_blocks, 256, 0, stream>>>(aggr, g_w1, g_b1, g_w2, g_b2, x, out, N);
}

// Round 6
// 345.480 us; speedup vs baseline: 1.2596x; 1.0853x over previous
//
#include <hip/hip_runtime.h>
#include <hip/hip_bf16.h>
#include <math.h>

// GNNConv rewrites:
//  (1) msg @ f_w = rel @ f_w[0:3] + x[src] @ f_w[3:]  -> per-node Yb (bf16) instead of per-edge GEMM
//  (2) dst-sorted aggregation (ushort src indices), wave-per-dst, zero atomics
//  (3) node_pre fuses delta + Yb; gemm_g_fused fuses both g-layers
//  (4) 64-row GEMM tiles, 2-way-free LDS bank layout, shfl delta reduction
//  (5) r6: aggregate processes 2 edges/iter (half-wave each, uint2 = 4 bf16 channels/lane),
//      unroll 4 -> 8 edges in flight; halves VMEM+shfl instruction count per edge

#define LEAKY(v) ((v) >= 0.0f ? (v) : 0.01f * (v))

static __device__ __forceinline__ unsigned short f2bf(float f) {
    unsigned u = __float_as_uint(f);
    u = (u + 0x7fffu + ((u >> 16) & 1u)) >> 16;   // RNE
    return (unsigned short)u;
}

// ---------------- node_pre: delta = tanh(leaky(x@h_w1+h_b1)@h_w2+h_b2); Yb = bf16(x@f_w[3:]+f_b) ----
__global__ __launch_bounds__(256) void node_pre(
    const float* __restrict__ x,
    const float* __restrict__ h_w1, const float* __restrict__ h_b1,
    const float* __restrict__ h_w2, const float* __restrict__ h_b2,
    const float* __restrict__ f_w3p,  // f_w + 3*128
    const float* __restrict__ f_b,
    float* __restrict__ delta,        // [N,3]
    unsigned short* __restrict__ Yb,  // [N,128] bf16
    int N)
{
    __shared__ float As[16][68];
    __shared__ float Wh[16][128];
    __shared__ float Wf[16][128];
    __shared__ float W2s[128][3];
    __shared__ float red[64][3];

    const int tid = threadIdx.x;
    const int bn  = blockIdx.x * 64;
    const int tx  = tid & 15;
    const int ty  = tid >> 4;

    if (tid < 128) {
        W2s[tid][0] = h_w2[tid * 3 + 0];
        W2s[tid][1] = h_w2[tid * 3 + 1];
        W2s[tid][2] = h_w2[tid * 3 + 2];
    }

    float acch[4][8], accf[4][8];
    #pragma unroll
    for (int i = 0; i < 4; ++i)
        #pragma unroll
        for (int j = 0; j < 8; ++j) { acch[i][j] = 0.f; accf[i][j] = 0.f; }

    #pragma unroll 1
    for (int k0 = 0; k0 < 128; k0 += 16) {
        {
            const int n  = tid >> 2;
            const int kq = (tid & 3) * 4;
            const int row = bn + n;
            float4 v = make_float4(0.f, 0.f, 0.f, 0.f);
            if (row < N) v = *(const float4*)(x + (size_t)row * 128 + k0 + kq);
            As[kq + 0][n] = v.x;
            As[kq + 1][n] = v.y;
            As[kq + 2][n] = v.z;
            As[kq + 3][n] = v.w;
        }
        {
            const int k = tid >> 4;
            const int j = (tid & 15) * 4;
            *(float4*)&Wh[k][j]      = *(const float4*)(h_w1  + (size_t)(k0 + k) * 128 + j);
            *(float4*)&Wh[k][j + 64] = *(const float4*)(h_w1  + (size_t)(k0 + k) * 128 + j + 64);
            *(float4*)&Wf[k][j]      = *(const float4*)(f_w3p + (size_t)(k0 + k) * 128 + j);
            *(float4*)&Wf[k][j + 64] = *(const float4*)(f_w3p + (size_t)(k0 + k) * 128 + j + 64);
        }
        __syncthreads();

        #pragma unroll
        for (int kk = 0; kk < 16; ++kk) {
            float a[4], wh[8], wf[8];
            *(float4*)&a[0]  = *(float4*)&As[kk][ty * 4];
            *(float4*)&wh[0] = *(float4*)&Wh[kk][tx * 4];
            *(float4*)&wh[4] = *(float4*)&Wh[kk][64 + tx * 4];
            *(float4*)&wf[0] = *(float4*)&Wf[kk][tx * 4];
            *(float4*)&wf[4] = *(float4*)&Wf[kk][64 + tx * 4];
            #pragma unroll
            for (int i = 0; i < 4; ++i)
                #pragma unroll
                for (int j = 0; j < 8; ++j) {
                    acch[i][j] += a[i] * wh[j];
                    accf[i][j] += a[i] * wf[j];
                }
        }
        __syncthreads();
    }

    #pragma unroll
    for (int i = 0; i < 4; ++i) {
        float p0 = 0.f, p1 = 0.f, p2 = 0.f;
        #pragma unroll
        for (int jj = 0; jj < 8; ++jj) {
            const int col = (jj < 4) ? (tx * 4 + jj) : (64 + tx * 4 + jj - 4);
            float h = acch[i][jj] + h_b1[col];
            h = LEAKY(h);
            p0 += h * W2s[col][0];
            p1 += h * W2s[col][1];
            p2 += h * W2s[col][2];
        }
        #pragma unroll
        for (int off = 8; off; off >>= 1) {
            p0 += __shfl_down(p0, off);
            p1 += __shfl_down(p1, off);
            p2 += __shfl_down(p2, off);
        }
        if (tx == 0) {
            const int rl = ty * 4 + i;
            red[rl][0] = p0; red[rl][1] = p1; red[rl][2] = p2;
        }
    }

    #pragma unroll
    for (int i = 0; i < 4; ++i) {
        const int row = bn + ty * 4 + i;
        if (row < N) {
            const int c0 = tx * 4;
            ushort4 u0, u1;
            u0.x = f2bf(accf[i][0] + f_b[c0 + 0]);
            u0.y = f2bf(accf[i][1] + f_b[c0 + 1]);
            u0.z = f2bf(accf[i][2] + f_b[c0 + 2]);
            u0.w = f2bf(accf[i][3] + f_b[c0 + 3]);
            u1.x = f2bf(accf[i][4] + f_b[64 + c0 + 0]);
            u1.y = f2bf(accf[i][5] + f_b[64 + c0 + 1]);
            u1.z = f2bf(accf[i][6] + f_b[64 + c0 + 2]);
            u1.w = f2bf(accf[i][7] + f_b[64 + c0 + 3]);
            *(ushort4*)(Yb + (size_t)row * 128 + c0)      = u0;
            *(ushort4*)(Yb + (size_t)row * 128 + 64 + c0) = u1;
        }
    }

    __syncthreads();
    if (tid < 64) {
        const int row = bn + tid;
        if (row < N) {
            delta[(size_t)row * 3 + 0] = tanhf(red[tid][0] + h_b2[0]);
            delta[(size_t)row * 3 + 1] = tanhf(red[tid][1] + h_b2[1]);
            delta[(size_t)row * 3 + 2] = tanhf(red[tid][2] + h_b2[2]);
        }
    }
}

// ---------------- counting sort of edges by dst ----------------
__global__ __launch_bounds__(256) void hist_kernel(
    const int* __restrict__ ei, int* __restrict__ counts, int E)
{
    const int e = blockIdx.x * 256 + threadIdx.x;
    if (e < E) atomicAdd(&counts[ei[(size_t)E + e]], 1);
}

__global__ __launch_bounds__(256) void scan_local(
    const int* __restrict__ counts, int* __restrict__ offs,
    int* __restrict__ blocksums, int N)
{
    __shared__ int s[256];
    const int tid  = threadIdx.x;
    const int base = blockIdx.x * 1024 + tid * 4;
    int v[4], sum = 0;
    #pragma unroll
    for (int j = 0; j < 4; ++j) {
        v[j] = (base + j < N) ? counts[base + j] : 0;
        sum += v[j];
    }
    s[tid] = sum;
    __syncthreads();
    for (int d = 1; d < 256; d <<= 1) {
        int t = (tid >= d) ? s[tid - d] : 0;
        __syncthreads();
        s[tid] += t;
        __syncthreads();
    }
    int run = s[tid] - sum;
    #pragma unroll
    for (int j = 0; j < 4; ++j) {
        if (base + j < N) offs[base + j] = run;
        run += v[j];
    }
    if (tid == 255) blocksums[blockIdx.x] = s[255];
}

__global__ __launch_bounds__(256) void scan_top(
    int* __restrict__ blocksums, int B)
{
    __shared__ int s[256];
    const int tid = threadIdx.x;
    int v[4], sum = 0;
    const int base = tid * 4;
    #pragma unroll
    for (int j = 0; j < 4; ++j) {
        v[j] = (base + j < B) ? blocksums[base + j] : 0;
        sum += v[j];
    }
    s[tid] = sum;
    __syncthreads();
    for (int d = 1; d < 256; d <<= 1) {
        int t = (tid >= d) ? s[tid - d] : 0;
        __syncthreads();
        s[tid] += t;
        __syncthreads();
    }
    int run = s[tid] - sum;
    #pragma unroll
    for (int j = 0; j < 4; ++j) {
        if (base + j < B) blocksums[base + j] = run;
        run += v[j];
    }
}

__global__ __launch_bounds__(256) void scan_fixup(
    int* __restrict__ offs, const int* __restrict__ blocksums, int N)
{
    const int i = blockIdx.x * 1024 + threadIdx.x * 4;
    const int add = blocksums[blockIdx.x];
    #pragma unroll
    for (int j = 0; j < 4; ++j)
        if (i + j < N) offs[i + j] += add;
}

__global__ __launch_bounds__(256) void scatter_kernel(
    const int* __restrict__ ei, int* __restrict__ offs,
    unsigned short* __restrict__ srcs_sorted, int E)
{
    const int e = blockIdx.x * 256 + threadIdx.x;
    if (e < E) {
        const int src = ei[e];
        const int dst = ei[(size_t)E + e];
        const int p = atomicAdd(&offs[dst], 1);
        srcs_sorted[p] = (unsigned short)src;   // N < 65536
    }
}

// ---------------- aggregation: wave-per-dst, 2 edges/iter (half-wave each) ----------------
// lane L: half = L>>5, channels cl = (L&31)*4. Per iteration: half 0 -> edge t, half 1 -> edge t+1.
// One uint2 (4 bf16) gather per lane per iteration. Final __shfl_xor(32) combine, float4 store.
__global__ __launch_bounds__(256) void aggregate_kernel(
    const unsigned short* __restrict__ srcs_sorted,
    const int* __restrict__ offs_end,      // start + count
    const int* __restrict__ counts,
    const float* __restrict__ pos,         // [N,3]
    const float* __restrict__ delta,       // [N,3]
    const unsigned short* __restrict__ Yb, // [N,128] bf16
    const float* __restrict__ fw3,         // [3][128]
    float* __restrict__ aggr,              // [N,128] = d_out
    int N)
{
    const int lane = threadIdx.x & 63;
    const int d = blockIdx.x * 4 + (threadIdx.x >> 6);
    if (d >= N) return;

    const int half = lane >> 5;
    const int cl   = (lane & 31) * 4;

    float wx[4], wy[4], wz[4];
    #pragma unroll
    for (int j = 0; j < 4; ++j) {
        wx[j] = fw3[cl + j];
        wy[j] = fw3[128 + cl + j];
        wz[j] = fw3[256 + cl + j];
    }

    const int len   = counts[d];
    const int start = offs_end[d] - len;
    const float q0 = delta[(size_t)d * 3 + 0] - pos[(size_t)d * 3 + 0];
    const float q1 = delta[(size_t)d * 3 + 1] - pos[(size_t)d * 3 + 1];
    const float q2 = delta[(size_t)d * 3 + 2] - pos[(size_t)d * 3 + 2];

    float acc[4] = {0.f, 0.f, 0.f, 0.f};

    for (int chunk = 0; chunk < len; chunk += 64) {
        const int m = min(64, len - chunk);
        int idx = 0; float rx = 0.f, ry = 0.f, rz = 0.f;
        if (lane < m) {
            idx = srcs_sorted[start + chunk + lane];
            rx = pos[(size_t)idx * 3 + 0] + q0;
            ry = pos[(size_t)idx * 3 + 1] + q1;
            rz = pos[(size_t)idx * 3 + 2] + q2;
        }
        int t = 0;
        #pragma unroll 4
        for (; t + 2 <= m; t += 2) {
            const int e = t + half;
            const int   s  = __shfl(idx, e);
            const float r0 = __shfl(rx, e);
            const float r1 = __shfl(ry, e);
            const float r2 = __shfl(rz, e);
            const uint2 y = *(const uint2*)(Yb + (size_t)s * 128 + cl);
            const float f0 = __uint_as_float((y.x & 0xffffu) << 16);
            const float f1 = __uint_as_float(y.x & 0xffff0000u);
            const float f2 = __uint_as_float((y.y & 0xffffu) << 16);
            const float f3 = __uint_as_float(y.y & 0xffff0000u);
            float z0 = f0 + r0 * wx[0] + r1 * wy[0] + r2 * wz[0];
            float z1 = f1 + r0 * wx[1] + r1 * wy[1] + r2 * wz[1];
            float z2 = f2 + r0 * wx[2] + r1 * wy[2] + r2 * wz[2];
            float z3 = f3 + r0 * wx[3] + r1 * wy[3] + r2 * wz[3];
            acc[0] += LEAKY(z0);
            acc[1] += LEAKY(z1);
            acc[2] += LEAKY(z2);
            acc[3] += LEAKY(z3);
        }
        if (t < m) {   // odd tail: half 0 only
            const int   s  = __shfl(idx, t);
            const float r0 = __shfl(rx, t);
            const float r1 = __shfl(ry, t);
            const float r2 = __shfl(rz, t);
            if (half == 0) {
                const uint2 y = *(const uint2*)(Yb + (size_t)s * 128 + cl);
                const float f0 = __uint_as_float((y.x & 0xffffu) << 16);
                const float f1 = __uint_as_float(y.x & 0xffff0000u);
                const float f2 = __uint_as_float((y.y & 0xffffu) << 16);
                const float f3 = __uint_as_float(y.y & 0xffff0000u);
                float z0 = f0 + r0 * wx[0] + r1 * wy[0] + r2 * wz[0];
                float z1 = f1 + r0 * wx[1] + r1 * wy[1] + r2 * wz[1];
                float z2 = f2 + r0 * wx[2] + r1 * wy[2] + r2 * wz[2];
                float z3 = f3 + r0 * wx[3] + r1 * wy[3] + r2 * wz[3];
                acc[0] += LEAKY(z0);
                acc[1] += LEAKY(z1);
                acc[2] += LEAKY(z2);
                acc[3] += LEAKY(z3);
            }
        }
    }

    #pragma unroll
    for (int j = 0; j < 4; ++j) acc[j] += __shfl_xor(acc[j], 32);
    if (half == 0)
        *(float4*)(aggr + (size_t)d * 128 + cl) =
            make_float4(acc[0], acc[1], acc[2], acc[3]);
}

// ---------------- fused g-MLP: out = leaky(aggr@g_w1+b1)@g_w2 + b2 + x (in-place aggr==out OK) ----
__global__ __launch_bounds__(256) void gemm_g_fused(
    const float* __restrict__ aggr,
    const float* __restrict__ g_w1, const float* __restrict__ g_b1,
    const float* __restrict__ g_w2, const float* __restrict__ g_b2,
    const float* __restrict__ x,
    float* __restrict__ out,
    int N)
{
    __shared__ float As[16][68];
    __shared__ float Ws[16][128];

    const int tid = threadIdx.x;
    const int bn  = blockIdx.x * 64;
    const int tx  = tid & 15;
    const int ty  = tid >> 4;

    float acc[4][8];
    #pragma unroll
    for (int i = 0; i < 4; ++i)
        #pragma unroll
        for (int j = 0; j < 8; ++j) acc[i][j] = 0.f;

    #pragma unroll 1
    for (int k0 = 0; k0 < 128; k0 += 16) {
        {
            const int n  = tid >> 2;
            const int kq = (tid & 3) * 4;
            const int row = bn + n;
            float4 v = make_float4(0.f, 0.f, 0.f, 0.f);
            if (row < N) v = *(const float4*)(aggr + (size_t)row * 128 + k0 + kq);
            As[kq + 0][n] = v.x;
            As[kq + 1][n] = v.y;
            As[kq + 2][n] = v.z;
            As[kq + 3][n] = v.w;
        }
        {
            const int k = tid >> 4;
            const int j = (tid & 15) * 4;
            *(float4*)&Ws[k][j]      = *(const float4*)(g_w1 + (size_t)(k0 + k) * 128 + j);
            *(float4*)&Ws[k][j + 64] = *(const float4*)(g_w1 + (size_t)(k0 + k) * 128 + j + 64);
        }
        __syncthreads();

        #pragma unroll
        for (int kk = 0; kk < 16; ++kk) {
            float a[4], w[8];
            *(float4*)&a[0] = *(float4*)&As[kk][ty * 4];
            *(float4*)&w[0] = *(float4*)&Ws[kk][tx * 4];
            *(float4*)&w[4] = *(float4*)&Ws[kk][64 + tx * 4];
            #pragma unroll
            for (int i = 0; i < 4; ++i)
                #pragma unroll
                for (int j = 0; j < 8; ++j)
                    acc[i][j] += a[i] * w[j];
        }
        __syncthreads();
    }

    float T[4][8];
    #pragma unroll
    for (int jj = 0; jj < 8; ++jj) {
        const int col = (jj < 4) ? (tx * 4 + jj) : (64 + tx * 4 + jj - 4);
        const float b = g_b1[col];
        #pragma unroll
        for (int i = 0; i < 4; ++i) {
            float t = acc[i][jj] + b;
            T[i][jj] = LEAKY(t);
        }
    }

    float acc2[4][8];
    #pragma unroll
    for (int i = 0; i < 4; ++i)
        #pragma unroll
        for (int j = 0; j < 8; ++j) acc2[i][j] = 0.f;

    #pragma unroll 1
    for (int k0 = 0; k0 < 128; k0 += 16) {
        {
            const int k = tid >> 4;
            const int j = (tid & 15) * 4;
            *(float4*)&Ws[k][j]      = *(const float4*)(g_w2 + (size_t)(k0 + k) * 128 + j);
            *(float4*)&Ws[k][j + 64] = *(const float4*)(g_w2 + (size_t)(k0 + k) * 128 + j + 64);
        }
        {
            const int kb   = (k0 < 64) ? k0 : (k0 - 64);
            const int txlo = kb >> 2;
            if (tx >= txlo && tx < txlo + 4) {
                const int jjb = (k0 < 64) ? 0 : 4;
                #pragma unroll
                for (int jo = 0; jo < 4; ++jo) {
                    const int kk = tx * 4 + jo - kb;
                    *(float4*)&As[kk][ty * 4] =
                        make_float4(T[0][jjb + jo], T[1][jjb + jo],
                                    T[2][jjb + jo], T[3][jjb + jo]);
                }
            }
        }
        __syncthreads();

        #pragma unroll
        for (int kk = 0; kk < 16; ++kk) {
            float a[4], w[8];
            *(float4*)&a[0] = *(float4*)&As[kk][ty * 4];
            *(float4*)&w[0] = *(float4*)&Ws[kk][tx * 4];
            *(float4*)&w[4] = *(float4*)&Ws[kk][64 + tx * 4];
            #pragma unroll
            for (int i = 0; i < 4; ++i)
                #pragma unroll
                for (int j = 0; j < 8; ++j)
                    acc2[i][j] += a[i] * w[j];
        }
        __syncthreads();
    }

    #pragma unroll
    for (int i = 0; i < 4; ++i) {
        const int row = bn + ty * 4 + i;
        if (row >= N) continue;
        const size_t base = (size_t)row * 128;
        const int c0 = tx * 4;
        float4 b0 = *(const float4*)(g_b2 + c0);
        float4 r0 = *(const float4*)(x + base + c0);
        float4 v0;
        v0.x = acc2[i][0] + b0.x + r0.x;
        v0.y = acc2[i][1] + b0.y + r0.y;
        v0.z = acc2[i][2] + b0.z + r0.z;
        v0.w = acc2[i][3] + b0.w + r0.w;
        *(float4*)(out + base + c0) = v0;
        float4 b1 = *(const float4*)(g_b2 + 64 + c0);
        float4 r1 = *(const float4*)(x + base + 64 + c0);
        float4 v1;
        v1.x = acc2[i][4] + b1.x + r1.x;
        v1.y = acc2[i][5] + b1.y + r1.y;
        v1.z = acc2[i][6] + b1.z + r1.z;
        v1.w = acc2[i][7] + b1.w + r1.w;
        *(float4*)(out + base + 64 + c0) = v1;
    }
}

// ---------------- launch ----------------
extern "C" void kernel_launch(void* const* d_in, const int* in_sizes, int n_in,
                              void* d_out, int out_size, void* d_ws, size_t ws_size,
                              hipStream_t stream) {
    const float* x    = (const float*)d_in[0];
    const float* pos  = (const float*)d_in[1];
    const int*   ei   = (const int*)d_in[2];
    const float* h_w1 = (const float*)d_in[3];
    const float* h_b1 = (const float*)d_in[4];
    const float* h_w2 = (const float*)d_in[5];
    const float* h_b2 = (const float*)d_in[6];
    const float* f_w  = (const float*)d_in[7];   // [131,128]
    const float* f_b  = (const float*)d_in[8];
    const float* g_w1 = (const float*)d_in[9];
    const float* g_b1 = (const float*)d_in[10];
    const float* g_w2 = (const float*)d_in[11];
    const float* g_b2 = (const float*)d_in[12];
    float* out = (float*)d_out;

    const int N = in_sizes[0] / 128;
    const int E = in_sizes[2] / 2;

    // ws (~15 MB): delta[N*3] f32 | Yb[N*128] bf16 | counts[N] | offs[N] | bsums[1024] | srcs[E] u16
    float* delta          = (float*)d_ws;
    unsigned short* Yb    = (unsigned short*)(delta + (size_t)N * 3);
    int* counts           = (int*)(Yb + (size_t)N * 128);
    int* offs             = counts + N;
    int* bsums            = offs + N;
    unsigned short* srcs  = (unsigned short*)(bsums + 1024);
    float* aggr           = out;

    const int tile_blocks = (N + 63) / 64;
    const int B = (N + 1023) / 1024;

    hipMemsetAsync(counts, 0, (size_t)N * sizeof(int), stream);

    node_pre<<<tile_blocks, 256, 0, stream>>>(x, h_w1, h_b1, h_w2, h_b2,
                                              f_w + 3 * 128, f_b, delta, Yb, N);

    hist_kernel<<<(E + 255) / 256, 256, 0, stream>>>(ei, counts, E);
    scan_local<<<B, 256, 0, stream>>>(counts, offs, bsums, N);
    scan_top<<<1, 256, 0, stream>>>(bsums, B);
    scan_fixup<<<B, 256, 0, stream>>>(offs, bsums, N);
    scatter_kernel<<<(E + 255) / 256, 256, 0, stream>>>(ei, offs, srcs, E);

    aggregate_kernel<<<(N + 3) / 4, 256, 0, stream>>>(
        srcs, offs, counts, pos, delta, Yb, f_w, aggr, N);

    gemm_g_fused<<<tile_blocks, 256, 0, stream>>>(aggr, g_w1, g_b1, g_w2, g_b2, x, out, N);
}

// Round 7
// 317.450 us; speedup vs baseline: 1.3708x; 1.0883x over previous
//
#include <hip/hip_runtime.h>
#include <hip/hip_bf16.h>
#include <math.h>

// GNNConv rewrites:
//  (1) msg @ f_w = rel @ f_w[0:3] + x[src] @ f_w[3:]  -> per-node Yb (bf16) instead of per-edge GEMM
//  (2) dst-sorted aggregation (ushort src indices), wave-per-dst, zero atomics
//  (3) node_pre fuses delta + Yb; gemm_g fuses both g-layers
//  (4) r7: both GEMM kernels on bf16 MFMA (16x16x32). Weights pre-transposed to bf16 W^T by
//      prep_weights each launch; A-frags converted fp32->bf16 in-register. node_pre has zero
//      LDS/barriers; gemm_g round-trips T through padded bf16 LDS between the two layers.

typedef __attribute__((ext_vector_type(8))) short bf16x8;
typedef __attribute__((ext_vector_type(4))) float f32x4;

#define LEAKY(v) ((v) >= 0.0f ? (v) : 0.01f * (v))

static __device__ __forceinline__ unsigned short f2bf(float f) {
    unsigned u = __float_as_uint(f);
    u = (u + 0x7fffu + ((u >> 16) & 1u)) >> 16;   // RNE
    return (unsigned short)u;
}

union ABu { unsigned short u[8]; bf16x8 v; };

static __device__ __forceinline__ bf16x8 cvt8(const float* __restrict__ p) {
    ABu r;
    const float4 v0 = *(const float4*)p;
    const float4 v1 = *(const float4*)(p + 4);
    r.u[0] = f2bf(v0.x); r.u[1] = f2bf(v0.y); r.u[2] = f2bf(v0.z); r.u[3] = f2bf(v0.w);
    r.u[4] = f2bf(v1.x); r.u[5] = f2bf(v1.y); r.u[6] = f2bf(v1.z); r.u[7] = f2bf(v1.w);
    return r.v;
}

static __device__ __forceinline__ bf16x8 zero_ab() {
    ABu r;
    #pragma unroll
    for (int i = 0; i < 8; ++i) r.u[i] = 0;
    return r.v;
}

// ---------------- weight prep: bf16 transposed copies (W^T[n][k]) ----------------
__global__ __launch_bounds__(128) void prep_weights(
    const float* __restrict__ h_w1, const float* __restrict__ f_w,
    const float* __restrict__ g_w1, const float* __restrict__ g_w2,
    unsigned short* __restrict__ Wht, unsigned short* __restrict__ Wft,
    unsigned short* __restrict__ G1t, unsigned short* __restrict__ G2t)
{
    const int j = blockIdx.x;      // output channel (row of W^T)
    const int k = threadIdx.x;     // k index
    Wht[j * 128 + k] = f2bf(h_w1[(size_t)k * 128 + j]);
    Wft[j * 128 + k] = f2bf(f_w[(size_t)(3 + k) * 128 + j]);
    G1t[j * 128 + k] = f2bf(g_w1[(size_t)k * 128 + j]);
    G2t[j * 128 + k] = f2bf(g_w2[(size_t)k * 128 + j]);
}

// ---------------- node_pre (MFMA): delta = tanh(leaky(x@h_w1+b1)@h_w2+b2); Yb = bf16(x@f_w[3:]+f_b)
// 4 waves/block, 16 rows/wave. No LDS, no barriers.
__global__ __launch_bounds__(256) void node_pre(
    const float* __restrict__ x,
    const unsigned short* __restrict__ Wht, const float* __restrict__ h_b1,
    const float* __restrict__ h_w2, const float* __restrict__ h_b2,
    const unsigned short* __restrict__ Wft, const float* __restrict__ f_b,
    float* __restrict__ delta, unsigned short* __restrict__ Yb, int N)
{
    const int lane = threadIdx.x & 63;
    const int wave = threadIdx.x >> 6;
    const int quad = lane >> 4;
    const int l16  = lane & 15;
    const int row0 = blockIdx.x * 64 + wave * 16;

    // A-fragments: A[m=l16][k=quad*8+j], 4 k-chunks of 32
    bf16x8 a[4];
    {
        const int row = row0 + l16;
        if (row < N) {
            const float* xp = x + (size_t)row * 128 + quad * 8;
            #pragma unroll
            for (int kc = 0; kc < 4; ++kc) a[kc] = cvt8(xp + kc * 32);
        } else {
            #pragma unroll
            for (int kc = 0; kc < 4; ++kc) a[kc] = zero_ab();
        }
    }

    f32x4 acch[8], accf[8];
    #pragma unroll
    for (int nt = 0; nt < 8; ++nt) {
        acch[nt] = (f32x4){0.f, 0.f, 0.f, 0.f};
        accf[nt] = (f32x4){0.f, 0.f, 0.f, 0.f};
    }

    #pragma unroll
    for (int nt = 0; nt < 8; ++nt) {
        const unsigned short* wh = Wht + (size_t)(nt * 16 + l16) * 128 + quad * 8;
        const unsigned short* wf = Wft + (size_t)(nt * 16 + l16) * 128 + quad * 8;
        #pragma unroll
        for (int kc = 0; kc < 4; ++kc) {
            const bf16x8 bh = *(const bf16x8*)(wh + kc * 32);
            const bf16x8 bf_ = *(const bf16x8*)(wf + kc * 32);
            acch[nt] = __builtin_amdgcn_mfma_f32_16x16x32_bf16(a[kc], bh, acch[nt], 0, 0, 0);
            accf[nt] = __builtin_amdgcn_mfma_f32_16x16x32_bf16(a[kc], bf_, accf[nt], 0, 0, 0);
        }
    }

    // Epilogue. C/D layout: col = nt*16 + l16, local row = quad*4 + reg.
    float p[4][3];
    #pragma unroll
    for (int r = 0; r < 4; ++r) { p[r][0] = 0.f; p[r][1] = 0.f; p[r][2] = 0.f; }

    #pragma unroll
    for (int nt = 0; nt < 8; ++nt) {
        const int col = nt * 16 + l16;
        const float b1 = h_b1[col];
        const float fb = f_b[col];
        const float w20 = h_w2[col * 3 + 0];
        const float w21 = h_w2[col * 3 + 1];
        const float w22 = h_w2[col * 3 + 2];
        #pragma unroll
        for (int reg = 0; reg < 4; ++reg) {
            const int grow = row0 + quad * 4 + reg;
            float h = acch[nt][reg] + b1;
            h = LEAKY(h);
            p[reg][0] += h * w20;
            p[reg][1] += h * w21;
            p[reg][2] += h * w22;
            if (grow < N)
                Yb[(size_t)grow * 128 + col] = f2bf(accf[nt][reg] + fb);
        }
    }

    // reduce p across the 16 l16 lanes (within quad)
    #pragma unroll
    for (int reg = 0; reg < 4; ++reg)
        #pragma unroll
        for (int c = 0; c < 3; ++c) {
            float v = p[reg][c];
            v += __shfl_down(v, 8);
            v += __shfl_down(v, 4);
            v += __shfl_down(v, 2);
            v += __shfl_down(v, 1);
            p[reg][c] = v;
        }

    if (l16 == 0) {
        #pragma unroll
        for (int reg = 0; reg < 4; ++reg) {
            const int grow = row0 + quad * 4 + reg;
            if (grow < N) {
                delta[(size_t)grow * 3 + 0] = tanhf(p[reg][0] + h_b2[0]);
                delta[(size_t)grow * 3 + 1] = tanhf(p[reg][1] + h_b2[1]);
                delta[(size_t)grow * 3 + 2] = tanhf(p[reg][2] + h_b2[2]);
            }
        }
    }
}

// ---------------- counting sort of edges by dst ----------------
__global__ __launch_bounds__(256) void hist_kernel(
    const int* __restrict__ ei, int* __restrict__ counts, int E)
{
    const int e = blockIdx.x * 256 + threadIdx.x;
    if (e < E) atomicAdd(&counts[ei[(size_t)E + e]], 1);
}

__global__ __launch_bounds__(256) void scan_local(
    const int* __restrict__ counts, int* __restrict__ offs,
    int* __restrict__ blocksums, int N)
{
    __shared__ int s[256];
    const int tid  = threadIdx.x;
    const int base = blockIdx.x * 1024 + tid * 4;
    int v[4], sum = 0;
    #pragma unroll
    for (int j = 0; j < 4; ++j) {
        v[j] = (base + j < N) ? counts[base + j] : 0;
        sum += v[j];
    }
    s[tid] = sum;
    __syncthreads();
    for (int d = 1; d < 256; d <<= 1) {
        int t = (tid >= d) ? s[tid - d] : 0;
        __syncthreads();
        s[tid] += t;
        __syncthreads();
    }
    int run = s[tid] - sum;
    #pragma unroll
    for (int j = 0; j < 4; ++j) {
        if (base + j < N) offs[base + j] = run;
        run += v[j];
    }
    if (tid == 255) blocksums[blockIdx.x] = s[255];
}

__global__ __launch_bounds__(256) void scan_top(
    int* __restrict__ blocksums, int B)
{
    __shared__ int s[256];
    const int tid = threadIdx.x;
    int v[4], sum = 0;
    const int base = tid * 4;
    #pragma unroll
    for (int j = 0; j < 4; ++j) {
        v[j] = (base + j < B) ? blocksums[base + j] : 0;
        sum += v[j];
    }
    s[tid] = sum;
    __syncthreads();
    for (int d = 1; d < 256; d <<= 1) {
        int t = (tid >= d) ? s[tid - d] : 0;
        __syncthreads();
        s[tid] += t;
        __syncthreads();
    }
    int run = s[tid] - sum;
    #pragma unroll
    for (int j = 0; j < 4; ++j) {
        if (base + j < B) blocksums[base + j] = run;
        run += v[j];
    }
}

__global__ __launch_bounds__(256) void scan_fixup(
    int* __restrict__ offs, const int* __restrict__ blocksums, int N)
{
    const int i = blockIdx.x * 1024 + threadIdx.x * 4;
    const int add = blocksums[blockIdx.x];
    #pragma unroll
    for (int j = 0; j < 4; ++j)
        if (i + j < N) offs[i + j] += add;
}

__global__ __launch_bounds__(256) void scatter_kernel(
    const int* __restrict__ ei, int* __restrict__ offs,
    unsigned short* __restrict__ srcs_sorted, int E)
{
    const int e = blockIdx.x * 256 + threadIdx.x;
    if (e < E) {
        const int src = ei[e];
        const int dst = ei[(size_t)E + e];
        const int p = atomicAdd(&offs[dst], 1);
        srcs_sorted[p] = (unsigned short)src;   // N < 65536
    }
}

// ---------------- aggregation: wave-per-dst, 2 edges/iter (half-wave each) ----------------
__global__ __launch_bounds__(256) void aggregate_kernel(
    const unsigned short* __restrict__ srcs_sorted,
    const int* __restrict__ offs_end,      // start + count
    const int* __restrict__ counts,
    const float* __restrict__ pos,         // [N,3]
    const float* __restrict__ delta,       // [N,3]
    const unsigned short* __restrict__ Yb, // [N,128] bf16
    const float* __restrict__ fw3,         // [3][128]
    float* __restrict__ aggr,              // [N,128] = d_out
    int N)
{
    const int lane = threadIdx.x & 63;
    const int d = blockIdx.x * 4 + (threadIdx.x >> 6);
    if (d >= N) return;

    const int half = lane >> 5;
    const int cl   = (lane & 31) * 4;

    float wx[4], wy[4], wz[4];
    #pragma unroll
    for (int j = 0; j < 4; ++j) {
        wx[j] = fw3[cl + j];
        wy[j] = fw3[128 + cl + j];
        wz[j] = fw3[256 + cl + j];
    }

    const int len   = counts[d];
    const int start = offs_end[d] - len;
    const float q0 = delta[(size_t)d * 3 + 0] - pos[(size_t)d * 3 + 0];
    const float q1 = delta[(size_t)d * 3 + 1] - pos[(size_t)d * 3 + 1];
    const float q2 = delta[(size_t)d * 3 + 2] - pos[(size_t)d * 3 + 2];

    float acc[4] = {0.f, 0.f, 0.f, 0.f};

    for (int chunk = 0; chunk < len; chunk += 64) {
        const int m = min(64, len - chunk);
        int idx = 0; float rx = 0.f, ry = 0.f, rz = 0.f;
        if (lane < m) {
            idx = srcs_sorted[start + chunk + lane];
            rx = pos[(size_t)idx * 3 + 0] + q0;
            ry = pos[(size_t)idx * 3 + 1] + q1;
            rz = pos[(size_t)idx * 3 + 2] + q2;
        }
        int t = 0;
        #pragma unroll 4
        for (; t + 2 <= m; t += 2) {
            const int e = t + half;
            const int   s  = __shfl(idx, e);
            const float r0 = __shfl(rx, e);
            const float r1 = __shfl(ry, e);
            const float r2 = __shfl(rz, e);
            const uint2 y = *(const uint2*)(Yb + (size_t)s * 128 + cl);
            const float f0 = __uint_as_float((y.x & 0xffffu) << 16);
            const float f1 = __uint_as_float(y.x & 0xffff0000u);
            const float f2 = __uint_as_float((y.y & 0xffffu) << 16);
            const float f3 = __uint_as_float(y.y & 0xffff0000u);
            float z0 = f0 + r0 * wx[0] + r1 * wy[0] + r2 * wz[0];
            float z1 = f1 + r0 * wx[1] + r1 * wy[1] + r2 * wz[1];
            float z2 = f2 + r0 * wx[2] + r1 * wy[2] + r2 * wz[2];
            float z3 = f3 + r0 * wx[3] + r1 * wy[3] + r2 * wz[3];
            acc[0] += LEAKY(z0);
            acc[1] += LEAKY(z1);
            acc[2] += LEAKY(z2);
            acc[3] += LEAKY(z3);
        }
        if (t < m) {
            const int   s  = __shfl(idx, t);
            const float r0 = __shfl(rx, t);
            const float r1 = __shfl(ry, t);
            const float r2 = __shfl(rz, t);
            if (half == 0) {
                const uint2 y = *(const uint2*)(Yb + (size_t)s * 128 + cl);
                const float f0 = __uint_as_float((y.x & 0xffffu) << 16);
                const float f1 = __uint_as_float(y.x & 0xffff0000u);
                const float f2 = __uint_as_float((y.y & 0xffffu) << 16);
                const float f3 = __uint_as_float(y.y & 0xffff0000u);
                float z0 = f0 + r0 * wx[0] + r1 * wy[0] + r2 * wz[0];
                float z1 = f1 + r0 * wx[1] + r1 * wy[1] + r2 * wz[1];
                float z2 = f2 + r0 * wx[2] + r1 * wy[2] + r2 * wz[2];
                float z3 = f3 + r0 * wx[3] + r1 * wy[3] + r2 * wz[3];
                acc[0] += LEAKY(z0);
                acc[1] += LEAKY(z1);
                acc[2] += LEAKY(z2);
                acc[3] += LEAKY(z3);
            }
        }
    }

    #pragma unroll
    for (int j = 0; j < 4; ++j) acc[j] += __shfl_xor(acc[j], 32);
    if (half == 0)
        *(float4*)(aggr + (size_t)d * 128 + cl) =
            make_float4(acc[0], acc[1], acc[2], acc[3]);
}

// ---------------- gemm_g (MFMA): out = leaky(aggr@g_w1+b1)@g_w2 + b2 + x (in-place aggr==out) ----
__global__ __launch_bounds__(256) void gemm_g(
    const float* __restrict__ aggr,
    const unsigned short* __restrict__ G1t, const float* __restrict__ g_b1,
    const unsigned short* __restrict__ G2t, const float* __restrict__ g_b2,
    const float* __restrict__ x,
    float* __restrict__ out, int N)
{
    __shared__ unsigned short Ts[64][136];   // +8 pad -> 2-way bank access on b128 reads

    const int lane = threadIdx.x & 63;
    const int wave = threadIdx.x >> 6;
    const int quad = lane >> 4;
    const int l16  = lane & 15;
    const int row0 = blockIdx.x * 64 + wave * 16;

    // phase 1: A from fp32 aggr
    bf16x8 a[4];
    {
        const int row = row0 + l16;
        if (row < N) {
            const float* ap = aggr + (size_t)row * 128 + quad * 8;
            #pragma unroll
            for (int kc = 0; kc < 4; ++kc) a[kc] = cvt8(ap + kc * 32);
        } else {
            #pragma unroll
            for (int kc = 0; kc < 4; ++kc) a[kc] = zero_ab();
        }
    }

    f32x4 acc[8];
    #pragma unroll
    for (int nt = 0; nt < 8; ++nt) acc[nt] = (f32x4){0.f, 0.f, 0.f, 0.f};

    #pragma unroll
    for (int nt = 0; nt < 8; ++nt) {
        const unsigned short* wp = G1t + (size_t)(nt * 16 + l16) * 128 + quad * 8;
        #pragma unroll
        for (int kc = 0; kc < 4; ++kc) {
            const bf16x8 b = *(const bf16x8*)(wp + kc * 32);
            acc[nt] = __builtin_amdgcn_mfma_f32_16x16x32_bf16(a[kc], b, acc[nt], 0, 0, 0);
        }
    }

    // T = leaky(acc + b1) -> bf16 LDS (C layout: col=nt*16+l16, row=wave*16+quad*4+reg)
    #pragma unroll
    for (int nt = 0; nt < 8; ++nt) {
        const int col = nt * 16 + l16;
        const float b1 = g_b1[col];
        #pragma unroll
        for (int reg = 0; reg < 4; ++reg) {
            float t = acc[nt][reg] + b1;
            t = LEAKY(t);
            Ts[wave * 16 + quad * 4 + reg][col] = f2bf(t);
        }
    }
    __syncthreads();

    // phase 2: A from LDS, B = G2t
    bf16x8 a2[4];
    {
        const unsigned short* tp = &Ts[wave * 16 + l16][quad * 8];
        #pragma unroll
        for (int kc = 0; kc < 4; ++kc) a2[kc] = *(const bf16x8*)(tp + kc * 32);
    }

    f32x4 acc2[8];
    #pragma unroll
    for (int nt = 0; nt < 8; ++nt) acc2[nt] = (f32x4){0.f, 0.f, 0.f, 0.f};

    #pragma unroll
    for (int nt = 0; nt < 8; ++nt) {
        const unsigned short* wp = G2t + (size_t)(nt * 16 + l16) * 128 + quad * 8;
        #pragma unroll
        for (int kc = 0; kc < 4; ++kc) {
            const bf16x8 b = *(const bf16x8*)(wp + kc * 32);
            acc2[nt] = __builtin_amdgcn_mfma_f32_16x16x32_bf16(a2[kc], b, acc2[nt], 0, 0, 0);
        }
    }

    // epilogue: + b2 + x
    #pragma unroll
    for (int nt = 0; nt < 8; ++nt) {
        const int col = nt * 16 + l16;
        const float b2 = g_b2[col];
        #pragma unroll
        for (int reg = 0; reg < 4; ++reg) {
            const int grow = row0 + quad * 4 + reg;
            if (grow < N)
                out[(size_t)grow * 128 + col] =
                    acc2[nt][reg] + b2 + x[(size_t)grow * 128 + col];
        }
    }
}

// ---------------- launch ----------------
extern "C" void kernel_launch(void* const* d_in, const int* in_sizes, int n_in,
                              void* d_out, int out_size, void* d_ws, size_t ws_size,
                              hipStream_t stream) {
    const float* x    = (const float*)d_in[0];
    const float* pos  = (const float*)d_in[1];
    const int*   ei   = (const int*)d_in[2];
    const float* h_w1 = (const float*)d_in[3];
    const float* h_b1 = (const float*)d_in[4];
    const float* h_w2 = (const float*)d_in[5];
    const float* h_b2 = (const float*)d_in[6];
    const float* f_w  = (const float*)d_in[7];   // [131,128]
    const float* f_b  = (const float*)d_in[8];
    const float* g_w1 = (const float*)d_in[9];
    const float* g_b1 = (const float*)d_in[10];
    const float* g_w2 = (const float*)d_in[11];
    const float* g_b2 = (const float*)d_in[12];
    float* out = (float*)d_out;

    const int N = in_sizes[0] / 128;
    const int E = in_sizes[2] / 2;

    // ws (~15.7 MB): delta[N*3]f32 | Yb[N*128]u16 | counts[N] | offs[N] | bsums[1024] |
    //                srcs[E]u16 | Wht/Wft/G1t/G2t [128*128]u16 each
    float* delta          = (float*)d_ws;
    unsigned short* Yb    = (unsigned short*)(delta + (size_t)N * 3);
    int* counts           = (int*)(Yb + (size_t)N * 128);
    int* offs             = counts + N;
    int* bsums            = offs + N;
    unsigned short* srcs  = (unsigned short*)(bsums + 1024);
    unsigned short* Wht   = srcs + (size_t)E;
    unsigned short* Wft   = Wht + 128 * 128;
    unsigned short* G1t   = Wft + 128 * 128;
    unsigned short* G2t   = G1t + 128 * 128;
    float* aggr           = out;

    const int tile_blocks = (N + 63) / 64;
    const int B = (N + 1023) / 1024;

    hipMemsetAsync(counts, 0, (size_t)N * sizeof(int), stream);

    prep_weights<<<128, 128, 0, stream>>>(h_w1, f_w, g_w1, g_w2, Wht, Wft, G1t, G2t);

    node_pre<<<tile_blocks, 256, 0, stream>>>(x, Wht, h_b1, h_w2, h_b2, Wft, f_b,
                                              delta, Yb, N);

    hist_kernel<<<(E + 255) / 256, 256, 0, stream>>>(ei, counts, E);
    scan_local<<<B, 256, 0, stream>>>(counts, offs, bsums, N);
    scan_top<<<1, 256, 0, stream>>>(bsums, B);
    scan_fixup<<<B, 256, 0, stream>>>(offs, bsums, N);
    scatter_kernel<<<(E + 255) / 256, 256, 0, stream>>>(ei, offs, srcs, E);

    aggregate_kernel<<<(N + 3) / 4, 256, 0, stream>>>(
        srcs, offs, counts, pos, delta, Yb, f_w, aggr, N);

    gemm_g<<<tile_blocks, 256, 0, stream>>>(aggr, G1t, g_b1, G2t, g_b2, x, out, N);
}